// Round 5
// baseline (509.780 us; speedup 1.0000x reference)
//
#include <hip/hip_runtime.h>

typedef __attribute__((ext_vector_type(4))) float f32x4;
typedef __attribute__((ext_vector_type(8))) short short8;

#define T_TOK 16384
#define D_DIM 4096
#define E_EXP 64
#define BKC 64
#define NCHUNK (D_DIM / BKC)     // 64
#define GAP_THR 0.05f
#define LIST_CAP 8192

// fp32 -> bf16 hi (truncate) + bf16 lo (truncate of exact residual).
// a = hi + lo + eps, |eps| <= 2^-16 |a|; 3-pass dot error ~1e-3 abs << GAP_THR.
__device__ __forceinline__ void cvt8(const f32x4& x, const f32x4& y,
                                     short8& hi, short8& lo) {
  float v[8] = {x[0], x[1], x[2], x[3], y[0], y[1], y[2], y[3]};
#pragma unroll
  for (int j = 0; j < 8; ++j) {
    unsigned b = __float_as_uint(v[j]);
    hi[j] = (short)(b >> 16);
    float l = v[j] - __uint_as_float(b & 0xffff0000u);
    lo[j] = (short)(__float_as_uint(l) >> 16);
  }
}

// Pre-convert eg [64 x 4096] -> bf16 hi/lo MFMA fragments in BKC=64 chunks.
// Unit u = (c*16 + sid)*64 + l, sid = p*8 + ks*4 + nt:
//   expert n = nt*16 + (l&15), k = c*64 + ks*32 + (l>>4)*8, 16 B per unit.
// Wave g reads: egb + c*8192 + p*4096 + ks*2048 + g*512 + lane*8.
// Also zeroes the fix-list counter.
__global__ __launch_bounds__(256)
void moe_precvt_kernel(const float* __restrict__ eg, short* __restrict__ egb,
                       int* __restrict__ cnt) {
  if (blockIdx.x == 0 && threadIdx.x == 0) *cnt = 0;
  int u = blockIdx.x * 256 + threadIdx.x;     // 65536 units
  int l = u & 63, sid = (u >> 6) & 15, c = u >> 10;
  int nt = sid & 3, ks = (sid >> 2) & 1, p = sid >> 3;
  int n = nt * 16 + (l & 15);
  int k = c * BKC + ks * 32 + (l >> 4) * 8;
  const float* src = eg + (size_t)n * D_DIM + k;
  f32x4 x = *(const f32x4*)src;
  f32x4 y = *(const f32x4*)(src + 4);
  short8 hi, lo;
  cvt8(x, y, hi, lo);
  *(short8*)&egb[(size_t)u * 8] = p ? lo : hi;
}

// Fused GEMM + top-2, barrier-free deep-pipelined main loop.
// Block: 16 tokens x 64 experts, 4 waves (wave g = one 16-expert group; all
// waves share A via L1). A: depth-4 register ring (HBM ~900cy); B: depth-2
// register ring from L2-resident egb (~250cy). sched_barrier(0) after each
// issue group pins loads at issue -> compiler emits counted vmcnt waits.
__global__ __launch_bounds__(256, 4)
void moe_main_kernel(const float* __restrict__ th, const short* __restrict__ egb,
                     const float* __restrict__ rl, const float* __restrict__ alpha_p,
                     float* __restrict__ out, int* __restrict__ cnt,
                     int* __restrict__ list) {
  __shared__ float gsc[16][68];                 // epilogue score exchange
  const int tid  = threadIdx.x;
  const int lane = tid & 63;
  const int g    = __builtin_amdgcn_readfirstlane(tid >> 6);  // expert group
  const int m    = lane & 15, quad = lane >> 4;
  const int tb   = blockIdx.x;
  const int tok  = tb * 16 + m;
  const float* aptr = th + (size_t)tok * D_DIM + quad * 8;
  const short* bptr = egb + g * 512 + lane * 8;

  f32x4 acc = (f32x4){0.f, 0.f, 0.f, 0.f};

  f32x4  a0[4], a1[4], a2[4], a3[4];   // A ring: 4 chunks in flight (64 VGPR)
  short8 b0[4], b1[4];                 // B ring: 2 chunks in flight (32 VGPR)

  auto loadA = [&](f32x4* pa, int c) {
    const float* ap = aptr + c * BKC;
    pa[0] = *(const f32x4*)ap;
    pa[1] = *(const f32x4*)(ap + 4);
    pa[2] = *(const f32x4*)(ap + 32);
    pa[3] = *(const f32x4*)(ap + 36);
  };
  auto loadB = [&](short8* pb, int c) {
    const short* bp = bptr + (size_t)c * 8192;
    pb[0] = *(const short8*)(bp);            // ks0 hi
    pb[1] = *(const short8*)(bp + 2048);     // ks1 hi
    pb[2] = *(const short8*)(bp + 4096);     // ks0 lo
    pb[3] = *(const short8*)(bp + 6144);     // ks1 lo
  };
  auto compute = [&](const f32x4* pa, const short8* pb) {
#pragma unroll
    for (int ks = 0; ks < 2; ++ks) {
      short8 ahi, alo;
      cvt8(pa[2 * ks], pa[2 * ks + 1], ahi, alo);
      acc = __builtin_amdgcn_mfma_f32_16x16x32_bf16(ahi, pb[ks],     acc, 0, 0, 0);
      acc = __builtin_amdgcn_mfma_f32_16x16x32_bf16(ahi, pb[2 + ks], acc, 0, 0, 0);
      acc = __builtin_amdgcn_mfma_f32_16x16x32_bf16(alo, pb[ks],     acc, 0, 0, 0);
    }
  };
  auto clampc = [](int c) { return c < NCHUNK ? c : NCHUNK - 1; };

  // Prologue: fill the rings.
  loadA(a0, 0); loadA(a1, 1); loadA(a2, 2); loadA(a3, 3);
  loadB(b0, 0); loadB(b1, 1);
  __builtin_amdgcn_sched_barrier(0);

#pragma unroll 1
  for (int cc = 0; cc < NCHUNK; cc += 4) {
    compute(a0, b0);                             // chunk cc
    loadA(a0, clampc(cc + 4));
    loadB(b0, clampc(cc + 2));
    __builtin_amdgcn_sched_barrier(0);
    compute(a1, b1);                             // chunk cc+1
    loadA(a1, clampc(cc + 5));
    loadB(b1, clampc(cc + 3));
    __builtin_amdgcn_sched_barrier(0);
    compute(a2, b0);                             // chunk cc+2
    loadA(a2, clampc(cc + 6));
    loadB(b0, clampc(cc + 4));
    __builtin_amdgcn_sched_barrier(0);
    compute(a3, b1);                             // chunk cc+3
    loadA(a3, clampc(cc + 7));
    loadB(b1, clampc(cc + 5));
    __builtin_amdgcn_sched_barrier(0);
  }

  // C/D layout: col(expert-within-group)=lane&15, row(token)=(lane>>4)*4+i
#pragma unroll
  for (int i = 0; i < 4; ++i)
    gsc[quad * 4 + i][g * 16 + m] = acc[i];
  __syncthreads();

  const float alpha = alpha_p[0];
#pragma unroll 1
  for (int tt = 0; tt < 4; ++tt) {
    int tl   = g * 4 + tt;
    int tokg = tb * 16 + tl;
    float gv = rl[(size_t)tokg * E_EXP + lane] + alpha * gsc[tl][lane];

    float v1 = gv; int i1 = lane;
#pragma unroll
    for (int off = 32; off > 0; off >>= 1) {
      float vo = __shfl_down(v1, off, 64);
      int   io = __shfl_down(i1, off, 64);
      if (vo > v1 || (vo == v1 && io < i1)) { v1 = vo; i1 = io; }
    }
    v1 = __shfl(v1, 0, 64); i1 = __shfl(i1, 0, 64);

    float g2 = (lane == i1) ? -3.4e38f : gv;
    float v2 = g2; int i2 = lane;
#pragma unroll
    for (int off = 32; off > 0; off >>= 1) {
      float vo = __shfl_down(v2, off, 64);
      int   io = __shfl_down(i2, off, 64);
      if (vo > v2 || (vo == v2 && io < i2)) { v2 = vo; i2 = io; }
    }
    v2 = __shfl(v2, 0, 64); i2 = __shfl(i2, 0, 64);

    // rank-2/3 near-tie also risks a wrong i2 -> flag for exact recheck
    float g3 = (lane == i1 || lane == i2) ? -3.4e38f : gv;
    float v3 = g3;
#pragma unroll
    for (int off = 32; off > 0; off >>= 1)
      v3 = fmaxf(v3, __shfl_down(v3, off, 64));

    if (lane == 0) {
      float ew  = __expf(v2 - v1);
      float inv = 1.f / (1.f + ew);
      ((float4*)out)[tokg] = make_float4((float)i1, inv, (float)i2, ew * inv);
      if (v1 - v2 < GAP_THR || v2 - v3 < GAP_THR) {
        int idx = atomicAdd(cnt, 1);
        if (idx < LIST_CAP) list[idx] = tokg;
      }
    }
  }
}

// Exact fp32 recompute of flagged tokens (4 waves split k, lane=expert).
__global__ __launch_bounds__(256)
void moe_fix_kernel(const float* __restrict__ th, const float* __restrict__ eg,
                    const float* __restrict__ rl, const float* __restrict__ alpha_p,
                    float* __restrict__ out, const int* __restrict__ cnt,
                    const int* __restrict__ list) {
  __shared__ float lds_p[4][64];
  const int wave = threadIdx.x >> 6, lane = threadIdx.x & 63;
  const float alpha = alpha_p[0];
  int count = *cnt;
  if (count > LIST_CAP) count = LIST_CAP;

  for (int i = blockIdx.x; i < count; i += gridDim.x) {
    int t = list[i];
    const float* tr = th + (size_t)t * D_DIM + wave * 1024;
    const float* er = eg + (size_t)lane * D_DIM + wave * 1024;
    float d = 0.f;
    for (int k = 0; k < 1024; k += 4) {
      float4 a = *(const float4*)(tr + k);
      float4 b = *(const float4*)(er + k);
      d = fmaf(a.x, b.x, d); d = fmaf(a.y, b.y, d);
      d = fmaf(a.z, b.z, d); d = fmaf(a.w, b.w, d);
    }
    lds_p[wave][lane] = d;
    __syncthreads();
    if (wave == 0) {
      float dot = lds_p[0][lane] + lds_p[1][lane] + lds_p[2][lane] + lds_p[3][lane];
      float g = rl[(size_t)t * E_EXP + lane] + alpha * dot;
      float v1 = g; int i1 = lane;
#pragma unroll
      for (int off = 32; off > 0; off >>= 1) {
        float vo = __shfl_down(v1, off, 64);
        int   io = __shfl_down(i1, off, 64);
        if (vo > v1 || (vo == v1 && io < i1)) { v1 = vo; i1 = io; }
      }
      v1 = __shfl(v1, 0, 64); i1 = __shfl(i1, 0, 64);
      float g2 = (lane == i1) ? -3.4e38f : g;
      float v2 = g2; int i2 = lane;
#pragma unroll
      for (int off = 32; off > 0; off >>= 1) {
        float vo = __shfl_down(v2, off, 64);
        int   io = __shfl_down(i2, off, 64);
        if (vo > v2 || (vo == v2 && io < i2)) { v2 = vo; i2 = io; }
      }
      if (lane == 0) {
        float ew  = __expf(v2 - v1);
        float inv = 1.f / (1.f + ew);
        ((float4*)out)[t] = make_float4((float)i1, inv, (float)i2, ew * inv);
      }
    }
    __syncthreads();
  }
}

extern "C" void kernel_launch(void* const* d_in, const int* in_sizes, int n_in,
                              void* d_out, int out_size, void* d_ws, size_t ws_size,
                              hipStream_t stream) {
  const float* th      = (const float*)d_in[0];  // [T, D]
  const float* rl      = (const float*)d_in[1];  // [T, E]
  const float* eg      = (const float*)d_in[2];  // [E, D]
  const float* alpha_p = (const float*)d_in[3];  // scalar
  float* out = (float*)d_out;                    // [T, 2, 2]

  short* egb = (short*)d_ws;                     // 1 MB bf16 hi/lo fragments
  int* cnt   = (int*)((char*)d_ws + (1 << 20));
  int* list  = cnt + 64;

  moe_precvt_kernel<<<256, 256, 0, stream>>>(eg, egb, cnt);
  moe_main_kernel<<<T_TOK / 16, 256, 0, stream>>>(th, egb, rl, alpha_p, out, cnt, list);
  moe_fix_kernel<<<256, 256, 0, stream>>>(th, eg, rl, alpha_p, out, cnt, list);
}

// Round 6
// 478.452 us; speedup vs baseline: 1.0655x; 1.0655x over previous
//
#include <hip/hip_runtime.h>

typedef __attribute__((ext_vector_type(4))) float f32x4;
typedef __attribute__((ext_vector_type(8))) short short8;

#define T_TOK 16384
#define D_DIM 4096
#define E_EXP 64
#define BKC 128
#define NCHUNK (D_DIM / BKC)     // 32
#define GAP_THR 0.05f
#define LIST_CAP 8192

typedef __attribute__((address_space(3))) uint32_t lds_u32;
typedef const __attribute__((address_space(1))) uint32_t glb_u32;

// fp32 -> bf16 hi (truncate) + bf16 lo (truncate of exact residual).
// a = hi + lo + eps, |eps| <= 2^-16 |a|; 3-pass dot error ~1e-3 abs << GAP_THR.
__device__ __forceinline__ void cvt8(const f32x4& x, const f32x4& y,
                                     short8& hi, short8& lo) {
  float v[8] = {x[0], x[1], x[2], x[3], y[0], y[1], y[2], y[3]};
#pragma unroll
  for (int j = 0; j < 8; ++j) {
    unsigned b = __float_as_uint(v[j]);
    hi[j] = (short)(b >> 16);
    float l = v[j] - __uint_as_float(b & 0xffff0000u);
    lo[j] = (short)(__float_as_uint(l) >> 16);
  }
}

// Pre-convert eg [64 x 4096] -> bf16 hi/lo MFMA fragments, BKC=128 chunks.
// Unit u = ((c*2+p)*16 + s)*64 + l, s = ks*4 + nt:
//   expert n = nt*16 + (l&15), k = c*128 + ks*32 + (l>>4)*8; 16 B per unit.
// Chunk c occupies egb[c*32768 .. +32768) bytes in exactly the order the main
// kernel stages it (lane-linear global_load_lds). Also zeroes fix counter.
__global__ __launch_bounds__(256)
void moe_precvt_kernel(const float* __restrict__ eg, short* __restrict__ egb,
                       int* __restrict__ cnt) {
  if (blockIdx.x == 0 && threadIdx.x == 0) *cnt = 0;
  int u = blockIdx.x * 256 + threadIdx.x;     // 65536 units
  int l = u & 63, s = (u >> 6) & 15, p = (u >> 10) & 1, c = u >> 11;
  int n = (s & 3) * 16 + (l & 15);
  int k = c * BKC + (s >> 2) * 32 + (l >> 4) * 8;
  const float* src = eg + (size_t)n * D_DIM + k;
  f32x4 x = *(const f32x4*)src;
  f32x4 y = *(const f32x4*)(src + 4);
  short8 hi, lo;
  cvt8(x, y, hi, lo);
  *(short8*)&egb[(size_t)u * 8] = p ? lo : hi;
}

// Fused GEMM + top-2 with the m201 counted-vmcnt pipeline:
// raw s_barrier + asm "s_waitcnt vmcnt(12)" keeps the next chunk's 12 VMEM
// ops (4 global_load_lds for B + 8 dwordx4 for A) in flight ACROSS barriers
// (a "memory"-clobber asm pins the loads; the compiler cannot sink them).
// Block: 32 tokens x 64 experts, 8 waves = (tg: token-16-group, g: expert-16-
// group); disjoint tokens per wave. 2 x 32 KB LDS -> 2 blocks/CU, 4 waves/SIMD.
__global__ __launch_bounds__(512, 4)
void moe_main_kernel(const float* __restrict__ th, const short* __restrict__ egb,
                     const float* __restrict__ rl, const float* __restrict__ alpha_p,
                     float* __restrict__ out, int* __restrict__ cnt,
                     int* __restrict__ list) {
  __shared__ __align__(16) short lds[2][16384];   // 2 x 32 KB
  const int tid  = threadIdx.x;
  const int lane = tid & 63;
  const int wu   = __builtin_amdgcn_readfirstlane(tid >> 6);  // 0..7
  const int tg   = wu >> 2, g = wu & 3;
  const int m    = lane & 15, quad = lane >> 4;
  const int tb   = blockIdx.x;
  const int tok  = tb * 32 + tg * 16 + m;
  const float* aptr = th + (size_t)tok * D_DIM + quad * 8;

  f32x4 acc = (f32x4){0.f, 0.f, 0.f, 0.f};
  f32x4 pa0[8], pa1[8];

  auto stage = [&](int c, int buf) {     // 2048 units, 512 thr -> 4 each
#pragma unroll
    for (int r = 0; r < 4; ++r) {
      int u = r * 512 + tid;                       // lane-linear dest
      const short* gp = egb + ((size_t)c * 2048 + u) * 8;
      __builtin_amdgcn_global_load_lds((glb_u32*)gp,
                                       (lds_u32*)&lds[buf][u * 8], 16, 0, 0);
    }
  };
  auto loadA = [&](f32x4* pa, int c) {
    const float* ap = aptr + c * BKC;
#pragma unroll
    for (int ks = 0; ks < 4; ++ks) {
      pa[2 * ks]     = *(const f32x4*)(ap + ks * 32);
      pa[2 * ks + 1] = *(const f32x4*)(ap + ks * 32 + 4);
    }
  };
  auto compute = [&](int buf, const f32x4* pa) {
#pragma unroll
    for (int ks = 0; ks < 4; ++ks) {
      short8 ahi, alo;
      cvt8(pa[2 * ks], pa[2 * ks + 1], ahi, alo);
      const int s = ks * 4 + g;
      short8 bhi = *(const short8*)&lds[buf][s * 512 + lane * 8];
      short8 blo = *(const short8*)&lds[buf][8192 + s * 512 + lane * 8];
      acc = __builtin_amdgcn_mfma_f32_16x16x32_bf16(ahi, bhi, acc, 0, 0, 0);
      acc = __builtin_amdgcn_mfma_f32_16x16x32_bf16(ahi, blo, acc, 0, 0, 0);
      acc = __builtin_amdgcn_mfma_f32_16x16x32_bf16(alo, bhi, acc, 0, 0, 0);
    }
  };

  stage(0, 0);
  loadA(pa0, 0);
#pragma unroll 1
  for (int cc = 0; cc < NCHUNK; cc += 2) {
    // chunk cc (buf0, pa0); prefetch cc+1 -> buf1, pa1
    stage(cc + 1, 1);
    loadA(pa1, cc + 1);
    asm volatile("s_waitcnt vmcnt(12)" ::: "memory");  // cc's 12 ops done
    __builtin_amdgcn_s_barrier();
    compute(0, pa0);
    __builtin_amdgcn_s_barrier();                       // buf0 free for re-stage
    // chunk cc+1 (buf1, pa1); prefetch cc+2 -> buf0, pa0
    if (cc + 2 < NCHUNK) {
      stage(cc + 2, 0);
      loadA(pa0, cc + 2);
      asm volatile("s_waitcnt vmcnt(12)" ::: "memory");
    } else {
      asm volatile("s_waitcnt vmcnt(0)" ::: "memory");
    }
    __builtin_amdgcn_s_barrier();
    compute(1, pa1);
    __builtin_amdgcn_s_barrier();
  }

  // Epilogue: scores into buf0 (all compute done), then wave-per-4-tokens top2.
  float* gsc = (float*)&lds[0][0];                 // [32][68]
#pragma unroll
  for (int i = 0; i < 4; ++i)
    gsc[(tg * 16 + quad * 4 + i) * 68 + g * 16 + m] = acc[i];
  __syncthreads();

  const float alpha = alpha_p[0];
#pragma unroll 1
  for (int tt = 0; tt < 4; ++tt) {
    int tl   = wu * 4 + tt;
    int tokg = tb * 32 + tl;
    float gv = rl[(size_t)tokg * E_EXP + lane] + alpha * gsc[tl * 68 + lane];

    float v1 = gv; int i1 = lane;
#pragma unroll
    for (int off = 32; off > 0; off >>= 1) {
      float vo = __shfl_down(v1, off, 64);
      int   io = __shfl_down(i1, off, 64);
      if (vo > v1 || (vo == v1 && io < i1)) { v1 = vo; i1 = io; }
    }
    v1 = __shfl(v1, 0, 64); i1 = __shfl(i1, 0, 64);

    float g2 = (lane == i1) ? -3.4e38f : gv;
    float v2 = g2; int i2 = lane;
#pragma unroll
    for (int off = 32; off > 0; off >>= 1) {
      float vo = __shfl_down(v2, off, 64);
      int   io = __shfl_down(i2, off, 64);
      if (vo > v2 || (vo == v2 && io < i2)) { v2 = vo; i2 = io; }
    }
    v2 = __shfl(v2, 0, 64); i2 = __shfl(i2, 0, 64);

    // rank-2/3 near-tie also risks a wrong i2 -> flag for exact recheck
    float g3 = (lane == i1 || lane == i2) ? -3.4e38f : gv;
    float v3 = g3;
#pragma unroll
    for (int off = 32; off > 0; off >>= 1)
      v3 = fmaxf(v3, __shfl_down(v3, off, 64));

    if (lane == 0) {
      float ew  = __expf(v2 - v1);
      float inv = 1.f / (1.f + ew);
      ((float4*)out)[tokg] = make_float4((float)i1, inv, (float)i2, ew * inv);
      if (v1 - v2 < GAP_THR || v2 - v3 < GAP_THR) {
        int idx = atomicAdd(cnt, 1);
        if (idx < LIST_CAP) list[idx] = tokg;
      }
    }
  }
}

// Exact fp32 recompute of flagged tokens (4 waves split k, lane=expert).
__global__ __launch_bounds__(256)
void moe_fix_kernel(const float* __restrict__ th, const float* __restrict__ eg,
                    const float* __restrict__ rl, const float* __restrict__ alpha_p,
                    float* __restrict__ out, const int* __restrict__ cnt,
                    const int* __restrict__ list) {
  __shared__ float lds_p[4][64];
  const int wave = threadIdx.x >> 6, lane = threadIdx.x & 63;
  const float alpha = alpha_p[0];
  int count = *cnt;
  if (count > LIST_CAP) count = LIST_CAP;

  for (int i = blockIdx.x; i < count; i += gridDim.x) {
    int t = list[i];
    const float* tr = th + (size_t)t * D_DIM + wave * 1024;
    const float* er = eg + (size_t)lane * D_DIM + wave * 1024;
    float d = 0.f;
    for (int k = 0; k < 1024; k += 4) {
      float4 a = *(const float4*)(tr + k);
      float4 b = *(const float4*)(er + k);
      d = fmaf(a.x, b.x, d); d = fmaf(a.y, b.y, d);
      d = fmaf(a.z, b.z, d); d = fmaf(a.w, b.w, d);
    }
    lds_p[wave][lane] = d;
    __syncthreads();
    if (wave == 0) {
      float dot = lds_p[0][lane] + lds_p[1][lane] + lds_p[2][lane] + lds_p[3][lane];
      float g = rl[(size_t)t * E_EXP + lane] + alpha * dot;
      float v1 = g; int i1 = lane;
#pragma unroll
      for (int off = 32; off > 0; off >>= 1) {
        float vo = __shfl_down(v1, off, 64);
        int   io = __shfl_down(i1, off, 64);
        if (vo > v1 || (vo == v1 && io < i1)) { v1 = vo; i1 = io; }
      }
      v1 = __shfl(v1, 0, 64); i1 = __shfl(i1, 0, 64);
      float g2 = (lane == i1) ? -3.4e38f : g;
      float v2 = g2; int i2 = lane;
#pragma unroll
      for (int off = 32; off > 0; off >>= 1) {
        float vo = __shfl_down(v2, off, 64);
        int   io = __shfl_down(i2, off, 64);
        if (vo > v2 || (vo == v2 && io < i2)) { v2 = vo; i2 = io; }
      }
      if (lane == 0) {
        float ew  = __expf(v2 - v1);
        float inv = 1.f / (1.f + ew);
        ((float4*)out)[t] = make_float4((float)i1, inv, (float)i2, ew * inv);
      }
    }
    __syncthreads();
  }
}

extern "C" void kernel_launch(void* const* d_in, const int* in_sizes, int n_in,
                              void* d_out, int out_size, void* d_ws, size_t ws_size,
                              hipStream_t stream) {
  const float* th      = (const float*)d_in[0];  // [T, D]
  const float* rl      = (const float*)d_in[1];  // [T, E]
  const float* eg      = (const float*)d_in[2];  // [E, D]
  const float* alpha_p = (const float*)d_in[3];  // scalar
  float* out = (float*)d_out;                    // [T, 2, 2]

  short* egb = (short*)d_ws;                     // 1 MB bf16 hi/lo fragments
  int* cnt   = (int*)((char*)d_ws + (1 << 20));
  int* list  = cnt + 64;

  moe_precvt_kernel<<<256, 256, 0, stream>>>(eg, egb, cnt);
  moe_main_kernel<<<T_TOK / 32, 512, 0, stream>>>(th, egb, rl, alpha_p, out, cnt, list);
  moe_fix_kernel<<<256, 256, 0, stream>>>(th, eg, rl, alpha_p, out, cnt, list);
}